// Round 4
// baseline (202.912 us; speedup 1.0000x reference)
//
#include <hip/hip_runtime.h>
#include <math.h>

#define TWO_H 4096
#define HALF_H 2048
#define NGROUPS 8
#define BLOCK 256

typedef int   vi4 __attribute__((ext_vector_type(4)));
typedef float vf4 __attribute__((ext_vector_type(4)));

// One block per row. Each thread handles 8 output columns.
__global__ __launch_bounds__(BLOCK) void swiglu_requant_kernel(
    const int* __restrict__ x,         // [N, 4096] int32
    const float* __restrict__ wscale,  // [G, 4096]
    const float* __restrict__ ascale,  // [N]
    const float* __restrict__ bias,    // [4096]
    const float* __restrict__ qscale,  // [G]
    const int* __restrict__ gindex,    // [G]
    int* __restrict__ out,             // [N, 2048] int32 (int8 values widened)
    int n_rows)
{
    const int row = blockIdx.x;
    if (row >= n_rows) return;
    const int t = threadIdx.x;

    // group id: gid = #(cumsum(gindex) <= row)  (searchsorted side="right")
    int gid = 0;
    {
        int cum = 0;
#pragma unroll
        for (int g = 0; g < NGROUPS; ++g) {
            cum += gindex[g];
            if (row >= cum) gid++;
        }
    }

    const float a_s = ascale[row];
    const float q_s = qscale[gid];

    const long  xbase = (long)row * TWO_H;
    const int   c0 = t * 8;                    // gate col start; up col = c0 + 2048

    // streaming loads of x: non-temporal (no reuse, keep out of L2)
    const vi4* xg = (const vi4*)(x + xbase + c0);
    const vi4* xu = (const vi4*)(x + xbase + HALF_H + c0);
    vi4 g0 = __builtin_nontemporal_load(xg);
    vi4 g1 = __builtin_nontemporal_load(xg + 1);
    vi4 u0 = __builtin_nontemporal_load(xu);
    vi4 u1 = __builtin_nontemporal_load(xu + 1);

    // scale/bias: reused across all rows -> normal cached loads
    const float* wrow = wscale + (long)gid * TWO_H;
    const vf4* wg = (const vf4*)(wrow + c0);
    const vf4* wu = (const vf4*)(wrow + HALF_H + c0);
    vf4 wg0 = wg[0], wg1 = wg[1];
    vf4 wu0 = wu[0], wu1 = wu[1];

    const vf4* bg = (const vf4*)(bias + c0);
    const vf4* bu = (const vf4*)(bias + HALF_H + c0);
    vf4 bg0 = bg[0], bg1 = bg[1];
    vf4 bu0 = bu[0], bu1 = bu[1];

    float gi[8] = {(float)g0.x, (float)g0.y, (float)g0.z, (float)g0.w,
                   (float)g1.x, (float)g1.y, (float)g1.z, (float)g1.w};
    float ui[8] = {(float)u0.x, (float)u0.y, (float)u0.z, (float)u0.w,
                   (float)u1.x, (float)u1.y, (float)u1.z, (float)u1.w};
    float bgx[8] = {bg0.x, bg0.y, bg0.z, bg0.w, bg1.x, bg1.y, bg1.z, bg1.w};
    float bux[8] = {bu0.x, bu0.y, bu0.z, bu0.w, bu1.x, bu1.y, bu1.z, bu1.w};
    float wgx[8] = {wg0.x, wg0.y, wg0.z, wg0.w, wg1.x, wg1.y, wg1.z, wg1.w};
    float wux[8] = {wu0.x, wu0.y, wu0.z, wu0.w, wu1.x, wu1.y, wu1.z, wu1.w};

    float o[8];
    float lmax = 0.0f;
#pragma unroll
    for (int i = 0; i < 8; ++i) {
        float gv = (gi[i] + bgx[i]) * wgx[i] * a_s;
        float uv = (ui[i] + bux[i]) * wux[i] * a_s;
        float sv = uv / (1.0f + __expf(-uv));   // silu(up), native v_exp_f32
        float ov = sv * gv * q_s;
        o[i] = ov;
        lmax = fmaxf(lmax, fabsf(ov));
    }

    // wave (64-lane) max reduce
#pragma unroll
    for (int m = 1; m < 64; m <<= 1)
        lmax = fmaxf(lmax, __shfl_xor(lmax, m, 64));

    __shared__ float smax[BLOCK / 64];
    if ((t & 63) == 0) smax[t >> 6] = lmax;
    __syncthreads();
    float mx = fmaxf(fmaxf(smax[0], smax[1]), fmaxf(smax[2], smax[3]));

    const float scale = 127.0f / mx;

    int w[8];
#pragma unroll
    for (int i = 0; i < 8; ++i) {
        float v = o[i] * scale;
        v = fminf(fmaxf(v, -128.0f), 127.0f);  // clip then round (matches ref)
        w[i] = (int)rintf(v);                   // round half-to-even
    }

    int* op = out + (long)row * HALF_H + c0;
    vi4 w0 = {w[0], w[1], w[2], w[3]};
    vi4 w1 = {w[4], w[5], w[6], w[7]};
    __builtin_nontemporal_store(w0, (vi4*)op);      // streaming write
    __builtin_nontemporal_store(w1, (vi4*)op + 1);
}

extern "C" void kernel_launch(void* const* d_in, const int* in_sizes, int n_in,
                              void* d_out, int out_size, void* d_ws, size_t ws_size,
                              hipStream_t stream) {
    const int*   x      = (const int*)d_in[0];
    const float* wscale = (const float*)d_in[1];
    const float* ascale = (const float*)d_in[2];
    const float* bias   = (const float*)d_in[3];
    const float* qscale = (const float*)d_in[4];
    const int*   gindex = (const int*)d_in[5];
    int* out = (int*)d_out;

    const int n_rows = in_sizes[0] / TWO_H;  // 32768

    swiglu_requant_kernel<<<n_rows, BLOCK, 0, stream>>>(
        x, wscale, ascale, bias, qscale, gindex, out, n_rows);
}

// Round 5
// 168.729 us; speedup vs baseline: 1.2026x; 1.2026x over previous
//
#include <hip/hip_runtime.h>
#include <math.h>

#define TWO_H 4096
#define HALF_H 2048
#define NGROUPS 8
#define BLOCK 256
#define GRID 2048   // 8192 waves total; 4 rows per wave at N=32768

typedef int   vi4 __attribute__((ext_vector_type(4)));
typedef float vf4 __attribute__((ext_vector_type(4)));

// One WAVE per row (64 lanes x 32 cols). No LDS, no barriers.
// Grid-stride over rows to keep block count at 2048.
__global__ __launch_bounds__(BLOCK) void swiglu_requant_kernel(
    const int* __restrict__ x,         // [N, 4096] int32
    const float* __restrict__ wscale,  // [G, 4096]
    const float* __restrict__ ascale,  // [N]
    const float* __restrict__ bias,    // [4096]
    const float* __restrict__ qscale,  // [G]
    const int* __restrict__ gindex,    // [G]
    int* __restrict__ out,             // [N, 2048] int32 (int8 values widened)
    int n_rows)
{
    const int lane   = threadIdx.x & 63;
    const int wid    = blockIdx.x * (BLOCK / 64) + (threadIdx.x >> 6);
    const int nwaves = gridDim.x * (BLOCK / 64);

    // group boundaries (cumsum) once, kept in registers (wave-uniform)
    int cum[NGROUPS];
    {
        int c = 0;
#pragma unroll
        for (int g = 0; g < NGROUPS; ++g) { c += gindex[g]; cum[g] = c; }
    }

    for (int row = wid; row < n_rows; row += nwaves) {
        int gid = 0;
#pragma unroll
        for (int g = 0; g < NGROUPS; ++g) gid += (row >= cum[g]) ? 1 : 0;

        const float a_s = ascale[row];
        const float q_s = qscale[gid];

        const int*   xrow = x + (long)row * TWO_H;
        const float* wrow = wscale + (long)gid * TWO_H;

        float o[32];
        float lmax = 0.0f;

#pragma unroll
        for (int c = 0; c < 4; ++c) {
            const int cg = c * 512 + lane * 8;   // gate col start for this chunk

            vi4 g0 = *(const vi4*)(xrow + cg);
            vi4 g1 = *(const vi4*)(xrow + cg + 4);
            vi4 u0 = *(const vi4*)(xrow + HALF_H + cg);
            vi4 u1 = *(const vi4*)(xrow + HALF_H + cg + 4);

            vf4 wg0 = *(const vf4*)(wrow + cg);
            vf4 wg1 = *(const vf4*)(wrow + cg + 4);
            vf4 wu0 = *(const vf4*)(wrow + HALF_H + cg);
            vf4 wu1 = *(const vf4*)(wrow + HALF_H + cg + 4);

            vf4 bg0 = *(const vf4*)(bias + cg);
            vf4 bg1 = *(const vf4*)(bias + cg + 4);
            vf4 bu0 = *(const vf4*)(bias + HALF_H + cg);
            vf4 bu1 = *(const vf4*)(bias + HALF_H + cg + 4);

            float gi[8] = {(float)g0.x, (float)g0.y, (float)g0.z, (float)g0.w,
                           (float)g1.x, (float)g1.y, (float)g1.z, (float)g1.w};
            float ui[8] = {(float)u0.x, (float)u0.y, (float)u0.z, (float)u0.w,
                           (float)u1.x, (float)u1.y, (float)u1.z, (float)u1.w};
            float wgx[8] = {wg0.x, wg0.y, wg0.z, wg0.w, wg1.x, wg1.y, wg1.z, wg1.w};
            float wux[8] = {wu0.x, wu0.y, wu0.z, wu0.w, wu1.x, wu1.y, wu1.z, wu1.w};
            float bgx[8] = {bg0.x, bg0.y, bg0.z, bg0.w, bg1.x, bg1.y, bg1.z, bg1.w};
            float bux[8] = {bu0.x, bu0.y, bu0.z, bu0.w, bu1.x, bu1.y, bu1.z, bu1.w};

#pragma unroll
            for (int i = 0; i < 8; ++i) {
                float gv = (gi[i] + bgx[i]) * wgx[i] * a_s;
                float uv = (ui[i] + bux[i]) * wux[i] * a_s;
                // silu(up) with native exp + native rcp (values are small; int8
                // output tolerance 2.54 >> approx error)
                float e  = __expf(-uv);
                float sv = uv * __builtin_amdgcn_rcpf(1.0f + e);
                float ov = sv * gv * q_s;
                o[c * 8 + i] = ov;
                lmax = fmaxf(lmax, fabsf(ov));
            }
        }

        // 64-lane max reduce, registers only
#pragma unroll
        for (int m = 1; m < 64; m <<= 1)
            lmax = fmaxf(lmax, __shfl_xor(lmax, m, 64));

        const float scale = 127.0f / lmax;   // precise (once per row)

        int* orow = out + (long)row * HALF_H;
#pragma unroll
        for (int c = 0; c < 4; ++c) {
            const int co = c * 512 + lane * 8;
            int w[8];
#pragma unroll
            for (int i = 0; i < 8; ++i) {
                float v = o[c * 8 + i] * scale;
                v = fminf(fmaxf(v, -128.0f), 127.0f);  // clip then round (matches ref)
                w[i] = (int)rintf(v);                   // round half-to-even
            }
            vi4 w0 = {w[0], w[1], w[2], w[3]};
            vi4 w1 = {w[4], w[5], w[6], w[7]};
            *(vi4*)(orow + co)     = w0;
            *(vi4*)(orow + co + 4) = w1;
        }
    }
}

extern "C" void kernel_launch(void* const* d_in, const int* in_sizes, int n_in,
                              void* d_out, int out_size, void* d_ws, size_t ws_size,
                              hipStream_t stream) {
    const int*   x      = (const int*)d_in[0];
    const float* wscale = (const float*)d_in[1];
    const float* ascale = (const float*)d_in[2];
    const float* bias   = (const float*)d_in[3];
    const float* qscale = (const float*)d_in[4];
    const int*   gindex = (const int*)d_in[5];
    int* out = (int*)d_out;

    const int n_rows = in_sizes[0] / TWO_H;  // 32768

    swiglu_requant_kernel<<<GRID, BLOCK, 0, stream>>>(
        x, wscale, ascale, bias, qscale, gindex, out, n_rows);
}